// Round 17
// baseline (89.285 us; speedup 1.0000x reference)
//
#include <hip/hip_runtime.h>
#include <hip/hip_fp16.h>
#include <math.h>

#define S_NEI 32

// ---------------- transpose 256x256 (WkT[e][f] = Wk[f][e]) ----------------
__global__ __launch_bounds__(256) void transpose256(const float* __restrict__ in,
                                                    float* __restrict__ outT) {
    __shared__ float tile[32][33];
    const int bx = blockIdx.x * 32, by = blockIdx.y * 32;
    const int x = threadIdx.x, y = threadIdx.y;  // 32 x 8
#pragma unroll
    for (int i = 0; i < 32; i += 8)
        tile[y + i][x] = in[(by + y + i) * 256 + bx + x];
    __syncthreads();
#pragma unroll
    for (int i = 0; i < 32; i += 8)
        outT[(bx + y + i) * 256 + by + x] = tile[x][y + i];
}

// ---------------- legacy 8x256 tile GEMM (for tiny precompute GEMMs) -------
template <int KT>
__device__ __forceinline__ void gemm_tile8(const float* __restrict__ A, int row0,
                                           const float* __restrict__ B,
                                           float acc[2][4], float* __restrict__ sA,
                                           float* __restrict__ sB) {
    const int t = threadIdx.x;
    const int tr = t >> 6, tc = t & 63;
    const int r = t >> 5;
    const int k1 = t & 31;
    const size_t arow = (size_t)(row0 + r) * KT;
    for (int kb = 0; kb < KT; kb += 32) {
        sA[k1 * 12 + r] = A[arow + kb + k1];
#pragma unroll
        for (int i = 0; i < 8; ++i) {
            *reinterpret_cast<float4*>(&sB[(i * 4 + tr) * 256 + tc * 4]) =
                *reinterpret_cast<const float4*>(&B[(size_t)(kb + i * 4 + tr) * 256 + tc * 4]);
        }
        __syncthreads();
#pragma unroll
        for (int k = 0; k < 32; ++k) {
            const float2 a2 = *reinterpret_cast<const float2*>(&sA[k * 12 + tr * 2]);
            const float4 b4 = *reinterpret_cast<const float4*>(&sB[k * 256 + tc * 4]);
            acc[0][0] += a2.x * b4.x; acc[0][1] += a2.x * b4.y;
            acc[0][2] += a2.x * b4.z; acc[0][3] += a2.x * b4.w;
            acc[1][0] += a2.y * b4.x; acc[1][1] += a2.y * b4.y;
            acc[1][2] += a2.y * b4.z; acc[1][3] += a2.y * b4.w;
        }
        __syncthreads();
    }
}

// Wqk=Wq@WkT, Wvc=Wv@Wc_top, Wmc=Wm@Wc_bot — OUTPUT IN FP16
__global__ __launch_bounds__(256) void precompute3(const float* __restrict__ Wq,
                                                   const float* __restrict__ Wv,
                                                   const float* __restrict__ Wm,
                                                   const float* __restrict__ Wc,
                                                   const float* __restrict__ WkT,
                                                   __half* __restrict__ Wqk,
                                                   __half* __restrict__ Wfused) {
    __shared__ float sA[32 * 12];
    __shared__ float sB[32 * 256];
    float acc[2][4] = {};
    const float *Ap, *Bp;
    __half* Cp;
    switch (blockIdx.y) {
        case 0: Ap = Wq; Bp = WkT; Cp = Wqk; break;
        case 1: Ap = Wv; Bp = Wc; Cp = Wfused; break;                    // rows 0..255
        default: Ap = Wm; Bp = Wc + 256 * 256; Cp = Wfused + 256 * 256; break;  // rows 256..511
    }
    const int row0 = blockIdx.x * 8;
    gemm_tile8<256>(Ap, row0, Bp, acc, sA, sB);
    const int tr = threadIdx.x >> 6, tc = threadIdx.x & 63;
#pragma unroll
    for (int i = 0; i < 2; ++i) {
        const __half2 h0 = __floats2half2_rn(acc[i][0], acc[i][1]);
        const __half2 h1 = __floats2half2_rn(acc[i][2], acc[i][3]);
        __half2* dst = reinterpret_cast<__half2*>(&Cp[(size_t)(row0 + tr * 2 + i) * 256 + tc * 4]);
        dst[0] = h0;
        dst[1] = h1;
    }
}

// bqk = bq@WkT ; bfull = bv@Wc_top + bm@Wc_bot + bc  (block per column)
__global__ __launch_bounds__(256) void bias_k(const float* __restrict__ bq,
                                              const float* __restrict__ bv,
                                              const float* __restrict__ bm,
                                              const float* __restrict__ bc,
                                              const float* __restrict__ Wc,
                                              const float* __restrict__ WkT,
                                              float* __restrict__ bqk,
                                              float* __restrict__ bfull) {
    const int c = blockIdx.x;
    const int e = threadIdx.x;
    const int w = e >> 6, l = e & 63;
    float a = bq[e] * WkT[e * 256 + c];
    float v = bv[e] * Wc[e * 256 + c] + bm[e] * Wc[(256 + e) * 256 + c];
    __shared__ float redA[4], redV[4];
#pragma unroll
    for (int off = 32; off; off >>= 1) { a += __shfl_xor(a, off); v += __shfl_xor(v, off); }
    if (l == 0) { redA[w] = a; redV[w] = v; }
    __syncthreads();
    if (e == 0) {
        bqk[c] = redA[0] + redA[1] + redA[2] + redA[3];
        bfull[c] = bc[c] + redV[0] + redV[1] + redV[2] + redV[3];
    }
}

// ---------------- fused per-2-node megakernel (grid 2048 = 8 blocks/CU) ----
// 256 thr / 4 waves. Wave w = K-quarter for GEMMs; (node w>>1, half w&1) for
// attention. Lane owns 4 cols. fp16 B-streams. LDS ~15.5 KB, aliased regions:
//   RA: sA (phase1 self rows) / sAF (phase3 input)      [4608 B]
//   RB: sP (GEMM partials) / sW+sM+sME (phase2 reduce)  [8256 B]
// SAF2 skew MUST be strictly increasing (injective) — R16's masked variant
// collided (SAF2(114)==SAF2(128)) and corrupted both GEMM A-operands.
// __launch_bounds__(256,2): min-waves>=4 forces 64-VGPR spill (R7/R8).

#define SAF2(k) ((k) * 2 + (((k) >> 3) << 1))

#define FMA24(a2, b4)                                                       \
    do {                                                                    \
        acc[0][0] += (a2).x * (b4).x; acc[0][1] += (a2).x * (b4).y;         \
        acc[0][2] += (a2).x * (b4).z; acc[0][3] += (a2).x * (b4).w;         \
        acc[1][0] += (a2).y * (b4).x; acc[1][1] += (a2).y * (b4).y;         \
        acc[1][2] += (a2).y * (b4).z; acc[1][3] += (a2).y * (b4).w;         \
    } while (0)

__device__ __forceinline__ float4 h4_to_f4(float2 raw) {
    const __half2* h = reinterpret_cast<const __half2*>(&raw);
    const float2 f0 = __half22float2(h[0]);
    const float2 f1 = __half22float2(h[1]);
    return make_float4(f0.x, f0.y, f1.x, f1.y);
}

__global__ __launch_bounds__(256, 2) void fused2(const float* __restrict__ id2feat,
                                                 const int* __restrict__ nodes,
                                                 const int* __restrict__ neigh_mean,
                                                 const int* __restrict__ neigh_attn,
                                                 const __half* __restrict__ Wqk,
                                                 const float* __restrict__ bqk,
                                                 const __half* __restrict__ Wfused,
                                                 const float* __restrict__ bfull,
                                                 float* __restrict__ out) {
    __shared__ __align__(16) char smem[15456];
    float* RA  = (float*)smem;                 // 1152 f: sA / sAF (SAF2 max 1149)
    float* RB  = (float*)(smem + 4608);        // 2064 f: sP / sW+sM+sME
    float* sQk = (float*)(smem + 12864);       // 520 f
    int*   sIA = (int*)(smem + 14944);         // 64
    int*   sIM = (int*)(smem + 15200);         // 64

    const int t = threadIdx.x;   // 256
    const int w = t >> 6, l = t & 63;
    const int kq = w;
    const int col4 = l * 4;
    const int row0 = blockIdx.x * 2;

    if (t < 64) sIA[t] = neigh_attn[(size_t)row0 * S_NEI + t];
    else if (t < 128) sIM[t - 64] = neigh_mean[(size_t)row0 * S_NEI + (t - 64)];

    // stage 2 self rows transposed: waves 0,1 read row w coalesced
    if (w < 2) {
        const float4 v = *reinterpret_cast<const float4*>(
            &id2feat[(size_t)nodes[row0 + w] * 256 + col4]);
        RA[SAF2(col4 + 0) + w] = v.x;
        RA[SAF2(col4 + 1) + w] = v.y;
        RA[SAF2(col4 + 2) + w] = v.z;
        RA[SAF2(col4 + 3) + w] = v.w;
    }
    __syncthreads();

    float acc[2][4] = {};

    // ---- phase 1: K-quarter [kq*64, +64), all 256 cols (fp16 B) ----
    {
        const __half* Bp = Wqk + (size_t)(kq * 64) * 256 + col4;
        float2 bufA[8], bufB[8];
#pragma unroll
        for (int j = 0; j < 8; ++j)
            bufA[j] = *reinterpret_cast<const float2*>(&Bp[(size_t)j * 256]);
        for (int kb = 0; kb < 64; kb += 16) {
#pragma unroll
            for (int j = 0; j < 8; ++j)
                bufB[j] = *reinterpret_cast<const float2*>(&Bp[(size_t)(kb + 8 + j) * 256]);
#pragma unroll
            for (int j = 0; j < 8; ++j) {
                const float2 a2 = *reinterpret_cast<const float2*>(&RA[SAF2(kq * 64 + kb + j)]);
                const float4 b4 = h4_to_f4(bufA[j]);
                FMA24(a2, b4);
            }
            if (kb + 16 < 64) {
#pragma unroll
                for (int j = 0; j < 8; ++j)
                    bufA[j] = *reinterpret_cast<const float2*>(&Bp[(size_t)(kb + 16 + j) * 256]);
            }
#pragma unroll
            for (int j = 0; j < 8; ++j) {
                const float2 a2 =
                    *reinterpret_cast<const float2*>(&RA[SAF2(kq * 64 + kb + 8 + j)]);
                const float4 b4 = h4_to_f4(bufB[j]);
                FMA24(a2, b4);
            }
        }
    }
    __syncthreads();  // sA dead
    if (kq) {
        float* p = RB + ((kq - 1) * 2) * 260 + col4;
#pragma unroll
        for (int r = 0; r < 2; ++r) {
            p[r * 260 + 0] = acc[r][0]; p[r * 260 + 1] = acc[r][1];
            p[r * 260 + 2] = acc[r][2]; p[r * 260 + 3] = acc[r][3];
        }
    }
    __syncthreads();
    if (kq == 0) {
        const float4 bq4 = *reinterpret_cast<const float4*>(&bqk[col4]);
#pragma unroll
        for (int r = 0; r < 2; ++r) {
            float v0 = acc[r][0] + bq4.x, v1 = acc[r][1] + bq4.y;
            float v2 = acc[r][2] + bq4.z, v3 = acc[r][3] + bq4.w;
#pragma unroll
            for (int s = 0; s < 3; ++s) {
                const float* p = RB + (s * 2 + r) * 260 + col4;
                v0 += p[0]; v1 += p[1]; v2 += p[2]; v3 += p[3];
            }
            sQk[r * 260 + col4 + 0] = v0; sQk[r * 260 + col4 + 1] = v1;
            sQk[r * 260 + col4 + 2] = v2; sQk[r * 260 + col4 + 3] = v3;
        }
    }
    __syncthreads();  // sQk ready, sP dead

    // ---- phase 2: wave w = (node w>>1, half w&1); 16 attn + 16 mean rows ----
    float4 wa = make_float4(0.f, 0.f, 0.f, 0.f);
    float4 macc = make_float4(0.f, 0.f, 0.f, 0.f);
    float m = -1e30f, e = 0.f;
    {
        const int b = w >> 1, h = w & 1;
        const float4 q = *reinterpret_cast<const float4*>(&sQk[b * 260 + col4]);
        const float4* f4 = reinterpret_cast<const float4*>(id2feat);
        const int* ia = sIA + b * 32 + h * 16;
        const int* im = sIM + b * 32 + h * 16;
#pragma unroll
        for (int cch = 0; cch < 2; ++cch) {
            float4 r[8];
#pragma unroll
            for (int j = 0; j < 8; ++j) r[j] = f4[(size_t)ia[cch * 8 + j] * 64 + l];
#pragma unroll
            for (int j = 0; j < 8; ++j) {
                const float4 v = f4[(size_t)im[cch * 8 + j] * 64 + l];
                macc.x += v.x; macc.y += v.y; macc.z += v.z; macc.w += v.w;
            }
            float p[8];
#pragma unroll
            for (int j = 0; j < 8; ++j) {
                float s = q.x * r[j].x + q.y * r[j].y + q.z * r[j].z + q.w * r[j].w;
#pragma unroll
                for (int off = 32; off; off >>= 1) s += __shfl_xor(s, off);
                p[j] = s;
            }
            float cm = p[0];
#pragma unroll
            for (int j = 1; j < 8; ++j) cm = fmaxf(cm, p[j]);
            const float newm = fmaxf(m, cm);
            const float sc = __expf(m - newm);
            e *= sc; wa.x *= sc; wa.y *= sc; wa.z *= sc; wa.w *= sc;
#pragma unroll
            for (int j = 0; j < 8; ++j) {
                const float g = __expf(p[j] - newm);
                e += g;
                wa.x += g * r[j].x; wa.y += g * r[j].y;
                wa.z += g * r[j].z; wa.w += g * r[j].w;
            }
            m = newm;
        }
    }
    // half-merge through RB (sP dead): sW [4][64]f4, sM [4][64]f4, sME [8]f
    {
        float4* sW = (float4*)RB;
        float4* sM = (float4*)(RB + 1024);
        float* sME = RB + 2048;
        sW[w * 64 + l] = wa;
        sM[w * 64 + l] = macc;
        if (l == 0) { sME[w * 2] = m; sME[w * 2 + 1] = e; }
    }
    __syncthreads();
    if ((w & 1) == 0) {
        const int b = w >> 1;
        const float4* sW = (const float4*)RB;
        const float4* sM = (const float4*)(RB + 1024);
        const float* sME = RB + 2048;
        const float m0 = sME[w * 2], e0 = sME[w * 2 + 1];
        const float m1 = sME[(w + 1) * 2], e1 = sME[(w + 1) * 2 + 1];
        const float M = fmaxf(m0, m1);
        const float f0 = __expf(m0 - M), f1 = __expf(m1 - M);
        const float inv = 1.0f / (e0 * f0 + e1 * f1);
        const float4 w0 = sW[w * 64 + l], w1 = sW[(w + 1) * 64 + l];
        const float4 c0 = sM[w * 64 + l], c1 = sM[(w + 1) * 64 + l];
        const float mixv[4] = {(w0.x * f0 + w1.x * f1) * inv, (w0.y * f0 + w1.y * f1) * inv,
                               (w0.z * f0 + w1.z * f1) * inv, (w0.w * f0 + w1.w * f1) * inv};
        const float mev[4] = {(c0.x + c1.x) * (1.f / 32), (c0.y + c1.y) * (1.f / 32),
                              (c0.z + c1.z) * (1.f / 32), (c0.w + c1.w) * (1.f / 32)};
#pragma unroll
        for (int c = 0; c < 4; ++c) {
            RA[SAF2(col4 + c) + b] = mixv[c];
            RA[SAF2(256 + col4 + c) + b] = mev[c];
        }
    }
    __syncthreads();  // sAF ready, sW/sM dead

    // ---- phase 3: K-quarter [kq*128, +128) of AF(2x512)@Wfused (fp16 B) ----
#pragma unroll
    for (int r = 0; r < 2; ++r)
#pragma unroll
        for (int c = 0; c < 4; ++c) acc[r][c] = 0.f;
    {
        const __half* Bp = Wfused + (size_t)(kq * 128) * 256 + col4;
        float2 bufA[8], bufB[8];
#pragma unroll
        for (int j = 0; j < 8; ++j)
            bufA[j] = *reinterpret_cast<const float2*>(&Bp[(size_t)j * 256]);
        for (int kb = 0; kb < 128; kb += 16) {
#pragma unroll
            for (int j = 0; j < 8; ++j)
                bufB[j] = *reinterpret_cast<const float2*>(&Bp[(size_t)(kb + 8 + j) * 256]);
#pragma unroll
            for (int j = 0; j < 8; ++j) {
                const float2 a2 =
                    *reinterpret_cast<const float2*>(&RA[SAF2(kq * 128 + kb + j)]);
                const float4 b4 = h4_to_f4(bufA[j]);
                FMA24(a2, b4);
            }
            if (kb + 16 < 128) {
#pragma unroll
                for (int j = 0; j < 8; ++j)
                    bufA[j] = *reinterpret_cast<const float2*>(&Bp[(size_t)(kb + 16 + j) * 256]);
            }
#pragma unroll
            for (int j = 0; j < 8; ++j) {
                const float2 a2 =
                    *reinterpret_cast<const float2*>(&RA[SAF2(kq * 128 + kb + 8 + j)]);
                const float4 b4 = h4_to_f4(bufB[j]);
                FMA24(a2, b4);
            }
        }
    }
    __syncthreads();  // sAF dead, sW/sM reads done
    if (kq) {
        float* p = RB + ((kq - 1) * 2) * 260 + col4;
#pragma unroll
        for (int r = 0; r < 2; ++r) {
            p[r * 260 + 0] = acc[r][0]; p[r * 260 + 1] = acc[r][1];
            p[r * 260 + 2] = acc[r][2]; p[r * 260 + 3] = acc[r][3];
        }
    }
    __syncthreads();
    if (kq == 0) {
        const float4 bf4 = *reinterpret_cast<const float4*>(&bfull[col4]);
#pragma unroll
        for (int r = 0; r < 2; ++r) {
            float v0 = acc[r][0] + bf4.x, v1 = acc[r][1] + bf4.y;
            float v2 = acc[r][2] + bf4.z, v3 = acc[r][3] + bf4.w;
#pragma unroll
            for (int s = 0; s < 3; ++s) {
                const float* p = RB + (s * 2 + r) * 260 + col4;
                v0 += p[0]; v1 += p[1]; v2 += p[2]; v3 += p[3];
            }
            v0 = tanhf(v0); v1 = tanhf(v1); v2 = tanhf(v2); v3 = tanhf(v3);
            float sq = v0 * v0 + v1 * v1 + v2 * v2 + v3 * v3;
#pragma unroll
            for (int off = 32; off; off >>= 1) sq += __shfl_xor(sq, off);
            const float invn = 1.0f / fmaxf(sqrtf(sq), 1e-12f);
            *reinterpret_cast<float4*>(&out[(size_t)(row0 + r) * 256 + col4]) =
                make_float4(v0 * invn, v1 * invn, v2 * invn, v3 * invn);
        }
    }
}

extern "C" void kernel_launch(void* const* d_in, const int* in_sizes, int n_in,
                              void* d_out, int out_size, void* d_ws, size_t ws_size,
                              hipStream_t stream) {
    const int* nodes      = (const int*)d_in[0];
    const int* neigh_mean = (const int*)d_in[1];
    const int* neigh_attn = (const int*)d_in[2];
    const float* id2feat  = (const float*)d_in[3];
    const float* Wm = (const float*)d_in[4];
    const float* bm = (const float*)d_in[5];
    const float* Wq = (const float*)d_in[6];
    const float* bq = (const float*)d_in[7];
    const float* Wk = (const float*)d_in[8];
    // d_in[9] = bk: cancels in softmax
    const float* Wv = (const float*)d_in[10];
    const float* bv = (const float*)d_in[11];
    const float* Wc = (const float*)d_in[12];
    const float* bc = (const float*)d_in[13];
    float* out = (float*)d_out;

    const int B = in_sizes[0];  // 4096

    float* ws      = (float*)d_ws;
    float* WkT     = ws;                          // 65536 f
    __half* Wqk_h  = (__half*)(ws + 65536);       // 65536 halves (32768 f slots)
    __half* Wfus_h = (__half*)(ws + 98304);       // 131072 halves (65536 f slots)
    float* bqk     = ws + 163840;                 // 256 f
    float* bfull   = ws + 164096;                 // 256 f

    transpose256<<<dim3(8, 8), dim3(32, 8), 0, stream>>>(Wk, WkT);
    precompute3<<<dim3(32, 3), 256, 0, stream>>>(Wq, Wv, Wm, Wc, WkT, Wqk_h, Wfus_h);
    bias_k<<<256, 256, 0, stream>>>(bq, bv, bm, bc, Wc, WkT, bqk, bfull);
    fused2<<<B / 2, 256, 0, stream>>>(id2feat, nodes, neigh_mean, neigh_attn,
                                      Wqk_h, bqk, Wfus_h, bfull, out);
}

// Round 18
// 77.890 us; speedup vs baseline: 1.1463x; 1.1463x over previous
//
#include <hip/hip_runtime.h>
#include <hip/hip_fp16.h>
#include <math.h>

#define S_NEI 32

// ---------------- transpose 256x256 (WkT[e][f] = Wk[f][e]) ----------------
__global__ __launch_bounds__(256) void transpose256(const float* __restrict__ in,
                                                    float* __restrict__ outT) {
    __shared__ float tile[32][33];
    const int bx = blockIdx.x * 32, by = blockIdx.y * 32;
    const int x = threadIdx.x, y = threadIdx.y;  // 32 x 8
#pragma unroll
    for (int i = 0; i < 32; i += 8)
        tile[y + i][x] = in[(by + y + i) * 256 + bx + x];
    __syncthreads();
#pragma unroll
    for (int i = 0; i < 32; i += 8)
        outT[(bx + y + i) * 256 + by + x] = tile[x][y + i];
}

// ---------------- legacy 8x256 tile GEMM (for tiny precompute GEMMs) -------
template <int KT>
__device__ __forceinline__ void gemm_tile8(const float* __restrict__ A, int row0,
                                           const float* __restrict__ B,
                                           float acc[2][4], float* __restrict__ sA,
                                           float* __restrict__ sB) {
    const int t = threadIdx.x;
    const int tr = t >> 6, tc = t & 63;
    const int r = t >> 5;
    const int k1 = t & 31;
    const size_t arow = (size_t)(row0 + r) * KT;
    for (int kb = 0; kb < KT; kb += 32) {
        sA[k1 * 12 + r] = A[arow + kb + k1];
#pragma unroll
        for (int i = 0; i < 8; ++i) {
            *reinterpret_cast<float4*>(&sB[(i * 4 + tr) * 256 + tc * 4]) =
                *reinterpret_cast<const float4*>(&B[(size_t)(kb + i * 4 + tr) * 256 + tc * 4]);
        }
        __syncthreads();
#pragma unroll
        for (int k = 0; k < 32; ++k) {
            const float2 a2 = *reinterpret_cast<const float2*>(&sA[k * 12 + tr * 2]);
            const float4 b4 = *reinterpret_cast<const float4*>(&sB[k * 256 + tc * 4]);
            acc[0][0] += a2.x * b4.x; acc[0][1] += a2.x * b4.y;
            acc[0][2] += a2.x * b4.z; acc[0][3] += a2.x * b4.w;
            acc[1][0] += a2.y * b4.x; acc[1][1] += a2.y * b4.y;
            acc[1][2] += a2.y * b4.z; acc[1][3] += a2.y * b4.w;
        }
        __syncthreads();
    }
}

// Wqk=Wq@WkT, Wvc=Wv@Wc_top, Wmc=Wm@Wc_bot — OUTPUT IN FP16
__global__ __launch_bounds__(256) void precompute3(const float* __restrict__ Wq,
                                                   const float* __restrict__ Wv,
                                                   const float* __restrict__ Wm,
                                                   const float* __restrict__ Wc,
                                                   const float* __restrict__ WkT,
                                                   __half* __restrict__ Wqk,
                                                   __half* __restrict__ Wfused) {
    __shared__ float sA[32 * 12];
    __shared__ float sB[32 * 256];
    float acc[2][4] = {};
    const float *Ap, *Bp;
    __half* Cp;
    switch (blockIdx.y) {
        case 0: Ap = Wq; Bp = WkT; Cp = Wqk; break;
        case 1: Ap = Wv; Bp = Wc; Cp = Wfused; break;                    // rows 0..255
        default: Ap = Wm; Bp = Wc + 256 * 256; Cp = Wfused + 256 * 256; break;  // rows 256..511
    }
    const int row0 = blockIdx.x * 8;
    gemm_tile8<256>(Ap, row0, Bp, acc, sA, sB);
    const int tr = threadIdx.x >> 6, tc = threadIdx.x & 63;
#pragma unroll
    for (int i = 0; i < 2; ++i) {
        const __half2 h0 = __floats2half2_rn(acc[i][0], acc[i][1]);
        const __half2 h1 = __floats2half2_rn(acc[i][2], acc[i][3]);
        __half2* dst = reinterpret_cast<__half2*>(&Cp[(size_t)(row0 + tr * 2 + i) * 256 + tc * 4]);
        dst[0] = h0;
        dst[1] = h1;
    }
}

// bqk = bq@WkT ; bfull = bv@Wc_top + bm@Wc_bot + bc  (block per column)
__global__ __launch_bounds__(256) void bias_k(const float* __restrict__ bq,
                                              const float* __restrict__ bv,
                                              const float* __restrict__ bm,
                                              const float* __restrict__ bc,
                                              const float* __restrict__ Wc,
                                              const float* __restrict__ WkT,
                                              float* __restrict__ bqk,
                                              float* __restrict__ bfull) {
    const int c = blockIdx.x;
    const int e = threadIdx.x;
    const int w = e >> 6, l = e & 63;
    float a = bq[e] * WkT[e * 256 + c];
    float v = bv[e] * Wc[e * 256 + c] + bm[e] * Wc[(256 + e) * 256 + c];
    __shared__ float redA[4], redV[4];
#pragma unroll
    for (int off = 32; off; off >>= 1) { a += __shfl_xor(a, off); v += __shfl_xor(v, off); }
    if (l == 0) { redA[w] = a; redV[w] = v; }
    __syncthreads();
    if (e == 0) {
        bqk[c] = redA[0] + redA[1] + redA[2] + redA[3];
        bfull[c] = bc[c] + redV[0] + redV[1] + redV[2] + redV[3];
    }
}

// ---------------- fused per-4-node megakernel (R9 base, fp16 B-streams) ----
// Wave w = K-quarter AND owns node b=w. Lane owns 4 cols.
// Phase 1: Qk = self(4x256)@Wqk_h + bqk
// Phase 2: attn+mean, 1 node/wave, online-softmax 8-row chunks
// Phase 3: out = normalize(tanh(AF(4x512)@Wfused_h + bfull))
// B streamed as fp16 (8 B per 4 cols): halves L2 weight traffic (786->393 MB)
// __launch_bounds__(256,2): min-waves>=4 forces 64-VGPR spill (R7/R8).

#define SAF4(k) ((k) * 4 + ((((k) >> 3)) << 2))

#define FMA44(a4, b4)                                                       \
    do {                                                                    \
        acc[0][0] += (a4).x * (b4).x; acc[0][1] += (a4).x * (b4).y;         \
        acc[0][2] += (a4).x * (b4).z; acc[0][3] += (a4).x * (b4).w;         \
        acc[1][0] += (a4).y * (b4).x; acc[1][1] += (a4).y * (b4).y;         \
        acc[1][2] += (a4).y * (b4).z; acc[1][3] += (a4).y * (b4).w;         \
        acc[2][0] += (a4).z * (b4).x; acc[2][1] += (a4).z * (b4).y;         \
        acc[2][2] += (a4).z * (b4).z; acc[2][3] += (a4).z * (b4).w;         \
        acc[3][0] += (a4).w * (b4).x; acc[3][1] += (a4).w * (b4).y;         \
        acc[3][2] += (a4).w * (b4).z; acc[3][3] += (a4).w * (b4).w;         \
    } while (0)

__device__ __forceinline__ float4 h4_to_f4(float2 raw) {
    const __half2* h = reinterpret_cast<const __half2*>(&raw);
    const float2 f0 = __half22float2(h[0]);
    const float2 f1 = __half22float2(h[1]);
    return make_float4(f0.x, f0.y, f1.x, f1.y);
}

__global__ __launch_bounds__(256, 2) void fused4(const float* __restrict__ id2feat,
                                                 const int* __restrict__ nodes,
                                                 const int* __restrict__ neigh_mean,
                                                 const int* __restrict__ neigh_attn,
                                                 const __half* __restrict__ Wqk,
                                                 const float* __restrict__ bqk,
                                                 const __half* __restrict__ Wfused,
                                                 const float* __restrict__ bfull,
                                                 float* __restrict__ out) {
    __shared__ __align__(16) char smem[18112];
    float* R0  = (float*)smem;               // 3120 floats: sA / sP / sAF aliased
    float* sQk = (float*)(smem + 12480);     // 1040 floats
    int*   sIA = (int*)(smem + 16640);       // 128
    int*   sIM = (int*)(smem + 17152);       // 128

    const int t = threadIdx.x;   // 256
    const int w = t >> 6, l = t & 63;
    const int kq = w;
    const int col4 = l * 4;
    const int row0 = blockIdx.x * 4;

    if (t < 128) sIA[t] = neigh_attn[(size_t)row0 * S_NEI + t];
    else sIM[t - 128] = neigh_mean[(size_t)row0 * S_NEI + (t - 128)];

    // stage 4 self rows transposed: wave w reads row w coalesced
    {
        const float4 v = *reinterpret_cast<const float4*>(
            &id2feat[(size_t)nodes[row0 + w] * 256 + col4]);
        R0[SAF4(col4 + 0) + w] = v.x;
        R0[SAF4(col4 + 1) + w] = v.y;
        R0[SAF4(col4 + 2) + w] = v.z;
        R0[SAF4(col4 + 3) + w] = v.w;
    }
    __syncthreads();

    float acc[4][4] = {};

    // ---- phase 1: K-quarter [kq*64, +64), all 256 cols (fp16 B) ----
    {
        const __half* Bp = Wqk + (size_t)(kq * 64) * 256 + col4;
        float2 bufA[8], bufB[8];
#pragma unroll
        for (int j = 0; j < 8; ++j)
            bufA[j] = *reinterpret_cast<const float2*>(&Bp[(size_t)j * 256]);
        for (int kb = 0; kb < 64; kb += 16) {
#pragma unroll
            for (int j = 0; j < 8; ++j)
                bufB[j] = *reinterpret_cast<const float2*>(&Bp[(size_t)(kb + 8 + j) * 256]);
#pragma unroll
            for (int j = 0; j < 8; ++j) {
                const float4 a4 = *reinterpret_cast<const float4*>(&R0[SAF4(kq * 64 + kb + j)]);
                const float4 b4 = h4_to_f4(bufA[j]);
                FMA44(a4, b4);
            }
            if (kb + 16 < 64) {
#pragma unroll
                for (int j = 0; j < 8; ++j)
                    bufA[j] = *reinterpret_cast<const float2*>(&Bp[(size_t)(kb + 16 + j) * 256]);
            }
#pragma unroll
            for (int j = 0; j < 8; ++j) {
                const float4 a4 =
                    *reinterpret_cast<const float4*>(&R0[SAF4(kq * 64 + kb + 8 + j)]);
                const float4 b4 = h4_to_f4(bufB[j]);
                FMA44(a4, b4);
            }
        }
    }
    __syncthreads();  // sA dead
    if (kq) {
        float* p = R0 + ((kq - 1) * 4) * 260 + col4;
#pragma unroll
        for (int r = 0; r < 4; ++r) {
            p[r * 260 + 0] = acc[r][0]; p[r * 260 + 1] = acc[r][1];
            p[r * 260 + 2] = acc[r][2]; p[r * 260 + 3] = acc[r][3];
        }
    }
    __syncthreads();
    if (kq == 0) {
        const float4 bq4 = *reinterpret_cast<const float4*>(&bqk[col4]);
#pragma unroll
        for (int r = 0; r < 4; ++r) {
            float v0 = acc[r][0] + bq4.x, v1 = acc[r][1] + bq4.y;
            float v2 = acc[r][2] + bq4.z, v3 = acc[r][3] + bq4.w;
#pragma unroll
            for (int s = 0; s < 3; ++s) {
                const float* p = R0 + (s * 4 + r) * 260 + col4;
                v0 += p[0]; v1 += p[1]; v2 += p[2]; v3 += p[3];
            }
            sQk[r * 260 + col4 + 0] = v0; sQk[r * 260 + col4 + 1] = v1;
            sQk[r * 260 + col4 + 2] = v2; sQk[r * 260 + col4 + 3] = v3;
        }
    }
    __syncthreads();  // sQk ready, sP dead

    // ---- phase 2: wave w owns node b=w; online softmax in 8-row chunks ----
    {
        const int b = w;
        const float4 q = *reinterpret_cast<const float4*>(&sQk[b * 260 + col4]);
        const float4* f4 = reinterpret_cast<const float4*>(id2feat);
        const int* ia = sIA + b * 32;
        const int* im = sIM + b * 32;
        float4 macc = make_float4(0.f, 0.f, 0.f, 0.f);
        float4 wa = make_float4(0.f, 0.f, 0.f, 0.f);
        float m = -1e30f, e = 0.f;
#pragma unroll
        for (int cch = 0; cch < 4; ++cch) {
            float4 r[8];
#pragma unroll
            for (int j = 0; j < 8; ++j) r[j] = f4[(size_t)ia[cch * 8 + j] * 64 + l];
#pragma unroll
            for (int j = 0; j < 8; ++j) {
                const float4 v = f4[(size_t)im[cch * 8 + j] * 64 + l];
                macc.x += v.x; macc.y += v.y; macc.z += v.z; macc.w += v.w;
            }
            float p[8];
#pragma unroll
            for (int j = 0; j < 8; ++j) {
                float s = q.x * r[j].x + q.y * r[j].y + q.z * r[j].z + q.w * r[j].w;
#pragma unroll
                for (int off = 32; off; off >>= 1) s += __shfl_xor(s, off);
                p[j] = s;
            }
            float cm = p[0];
#pragma unroll
            for (int j = 1; j < 8; ++j) cm = fmaxf(cm, p[j]);
            const float newm = fmaxf(m, cm);
            const float sc = __expf(m - newm);
            e *= sc; wa.x *= sc; wa.y *= sc; wa.z *= sc; wa.w *= sc;
#pragma unroll
            for (int j = 0; j < 8; ++j) {
                const float g = __expf(p[j] - newm);
                e += g;
                wa.x += g * r[j].x; wa.y += g * r[j].y;
                wa.z += g * r[j].z; wa.w += g * r[j].w;
            }
            m = newm;
        }
        const float inv = 1.0f / e;
        const float mixv[4] = {wa.x * inv, wa.y * inv, wa.z * inv, wa.w * inv};
        const float mev[4] = {macc.x * (1.f / 32), macc.y * (1.f / 32),
                              macc.z * (1.f / 32), macc.w * (1.f / 32)};
        // AF transposed: mix -> cols [0,256), mean -> cols [256,512)
#pragma unroll
        for (int c = 0; c < 4; ++c) {
            R0[SAF4(col4 + c) + b] = mixv[c];
            R0[SAF4(256 + col4 + c) + b] = mev[c];
        }
    }
    __syncthreads();  // sAF ready

    // ---- phase 3: K-quarter [kq*128, +128) of AF(4x512)@Wfused (fp16 B) ----
#pragma unroll
    for (int r = 0; r < 4; ++r)
#pragma unroll
        for (int c = 0; c < 4; ++c) acc[r][c] = 0.f;
    {
        const __half* Bp = Wfused + (size_t)(kq * 128) * 256 + col4;
        float2 bufA[8], bufB[8];
#pragma unroll
        for (int j = 0; j < 8; ++j)
            bufA[j] = *reinterpret_cast<const float2*>(&Bp[(size_t)j * 256]);
        for (int kb = 0; kb < 128; kb += 16) {
#pragma unroll
            for (int j = 0; j < 8; ++j)
                bufB[j] = *reinterpret_cast<const float2*>(&Bp[(size_t)(kb + 8 + j) * 256]);
#pragma unroll
            for (int j = 0; j < 8; ++j) {
                const float4 a4 =
                    *reinterpret_cast<const float4*>(&R0[SAF4(kq * 128 + kb + j)]);
                const float4 b4 = h4_to_f4(bufA[j]);
                FMA44(a4, b4);
            }
            if (kb + 16 < 128) {
#pragma unroll
                for (int j = 0; j < 8; ++j)
                    bufA[j] = *reinterpret_cast<const float2*>(&Bp[(size_t)(kb + 16 + j) * 256]);
            }
#pragma unroll
            for (int j = 0; j < 8; ++j) {
                const float4 a4 =
                    *reinterpret_cast<const float4*>(&R0[SAF4(kq * 128 + kb + 8 + j)]);
                const float4 b4 = h4_to_f4(bufB[j]);
                FMA44(a4, b4);
            }
        }
    }
    __syncthreads();  // sAF dead
    if (kq) {
        float* p = R0 + ((kq - 1) * 4) * 260 + col4;
#pragma unroll
        for (int r = 0; r < 4; ++r) {
            p[r * 260 + 0] = acc[r][0]; p[r * 260 + 1] = acc[r][1];
            p[r * 260 + 2] = acc[r][2]; p[r * 260 + 3] = acc[r][3];
        }
    }
    __syncthreads();
    if (kq == 0) {
        const float4 bf4 = *reinterpret_cast<const float4*>(&bfull[col4]);
#pragma unroll
        for (int r = 0; r < 4; ++r) {
            float v0 = acc[r][0] + bf4.x, v1 = acc[r][1] + bf4.y;
            float v2 = acc[r][2] + bf4.z, v3 = acc[r][3] + bf4.w;
#pragma unroll
            for (int s = 0; s < 3; ++s) {
                const float* p = R0 + (s * 4 + r) * 260 + col4;
                v0 += p[0]; v1 += p[1]; v2 += p[2]; v3 += p[3];
            }
            v0 = tanhf(v0); v1 = tanhf(v1); v2 = tanhf(v2); v3 = tanhf(v3);
            float sq = v0 * v0 + v1 * v1 + v2 * v2 + v3 * v3;
#pragma unroll
            for (int off = 32; off; off >>= 1) sq += __shfl_xor(sq, off);
            const float invn = 1.0f / fmaxf(sqrtf(sq), 1e-12f);
            *reinterpret_cast<float4*>(&out[(size_t)(row0 + r) * 256 + col4]) =
                make_float4(v0 * invn, v1 * invn, v2 * invn, v3 * invn);
        }
    }
}

extern "C" void kernel_launch(void* const* d_in, const int* in_sizes, int n_in,
                              void* d_out, int out_size, void* d_ws, size_t ws_size,
                              hipStream_t stream) {
    const int* nodes      = (const int*)d_in[0];
    const int* neigh_mean = (const int*)d_in[1];
    const int* neigh_attn = (const int*)d_in[2];
    const float* id2feat  = (const float*)d_in[3];
    const float* Wm = (const float*)d_in[4];
    const float* bm = (const float*)d_in[5];
    const float* Wq = (const float*)d_in[6];
    const float* bq = (const float*)d_in[7];
    const float* Wk = (const float*)d_in[8];
    // d_in[9] = bk: cancels in softmax
    const float* Wv = (const float*)d_in[10];
    const float* bv = (const float*)d_in[11];
    const float* Wc = (const float*)d_in[12];
    const float* bc = (const float*)d_in[13];
    float* out = (float*)d_out;

    const int B = in_sizes[0];  // 4096

    float* ws      = (float*)d_ws;
    float* WkT     = ws;                          // 65536 f
    __half* Wqk_h  = (__half*)(ws + 65536);       // 65536 halves (32768 f slots)
    __half* Wfus_h = (__half*)(ws + 98304);       // 131072 halves (65536 f slots)
    float* bqk     = ws + 163840;                 // 256 f
    float* bfull   = ws + 164096;                 // 256 f

    transpose256<<<dim3(8, 8), dim3(32, 8), 0, stream>>>(Wk, WkT);
    precompute3<<<dim3(32, 3), 256, 0, stream>>>(Wq, Wv, Wm, Wc, WkT, Wqk_h, Wfus_h);
    bias_k<<<256, 256, 0, stream>>>(bq, bv, bm, bc, Wc, WkT, bqk, bfull);
    fused4<<<B / 4, 256, 0, stream>>>(id2feat, nodes, neigh_mean, neigh_attn,
                                      Wqk_h, bqk, Wfus_h, bfull, out);
}